// Round 5
// baseline (1154.464 us; speedup 1.0000x reference)
//
#include <hip/hip_runtime.h>
#include <math.h>

#define NB 4
#define P 2048
#define DF 64
#define EPS 0.1f
#define INV_EPS 10.0f
#define MAX_ITER 50
#define NBLK 256   // 1 block per CU (cooperative, co-resident)
#define TPB 512    // 8 waves
#define TS 256     // tile size: each block owns a 256x256 tile of C
// base-2 log domain: creg = C * INV_EPS * log2(e); cost = sum(pi*creg)*EPS*ln2
#define SCALE 14.426950408889634f
#define C2N 0.069314718055994531f
#define PARF (NB * 8 * 8 * TS)  // floats per parity buffer (65536)

typedef float vfloat4 __attribute__((ext_vector_type(4)));  // native vec for nt-store

#if __has_builtin(__builtin_amdgcn_exp2f)
#define EXP2(x) __builtin_amdgcn_exp2f(x)
#else
#define EXP2(x) exp2f(x)
#endif
#if __has_builtin(__builtin_amdgcn_logf)
#define LOG2(x) __builtin_amdgcn_logf(x)
#else
#define LOG2(x) log2f(x)
#endif

struct BuildMem { float xs[32 * 260]; float ys[32 * 260]; };                // 66.6 KB
struct IterMem  { float rin[8 * 260]; float red[260]; float cw[8 * 260]; }; // 17.7 KB
union SMem { BuildMem b; IterMem c; };

// ---------------------------------------------------------------------------
// Agent-coherent (L2-bypassing) data movement. Relaxed atomics at AGENT
// scope. Visibility protocol (HW-verified rounds 0-4):
//   writer: stores -> __threadfence_block+__syncthreads (vmcnt drain; a
//           retired sc1 store is visible device-wide) -> t0 stamps flag
//   reader: poll flags in PARALLEL -> __syncthreads -> sc1 data loads
// ---------------------------------------------------------------------------
__device__ __forceinline__ void flag_store(unsigned* f, unsigned v) {
  __hip_atomic_store(f, v, __ATOMIC_RELAXED, __HIP_MEMORY_SCOPE_AGENT);
}
__device__ __forceinline__ unsigned flag_load(unsigned* f) {
  return __hip_atomic_load(f, __ATOMIC_RELAXED, __HIP_MEMORY_SCOPE_AGENT);
}
__device__ __forceinline__ void store_f2_agent(float* p, float a, float b) {
  unsigned long long bits =
      ((unsigned long long)__float_as_uint(b) << 32) | __float_as_uint(a);
  __hip_atomic_store((unsigned long long*)p, bits, __ATOMIC_RELAXED,
                     __HIP_MEMORY_SCOPE_AGENT);
}
__device__ __forceinline__ float2 load_f2_agent(const float* p) {
  unsigned long long bits = __hip_atomic_load((unsigned long long*)p,
      __ATOMIC_RELAXED, __HIP_MEMORY_SCOPE_AGENT);
  return make_float2(__uint_as_float((unsigned)bits),
                     __uint_as_float((unsigned)(bits >> 32)));
}
__device__ __forceinline__ void store_f_agent(float* p, float v) {
  __hip_atomic_store(p, v, __ATOMIC_RELAXED, __HIP_MEMORY_SCOPE_AGENT);
}

// LSE2 merge of (M,S) with (om,os): one exp2 (the max side's factor is 1).
__device__ __forceinline__ void lse_merge(float& M, float& S, float om, float os) {
  float d = EXP2(-fabsf(M - om));
  float Sn = (M >= om) ? fmaf(os, d, S) : fmaf(S, d, os);
  M = fmaxf(M, om);
  S = Sn;
}

// ---------------------------------------------------------------------------
// 2D-tiled persistent cooperative kernel. Block b -> (batch n = b>>6,
// bi = (b>>3)&7, bj = b&7): owns the 256x256 tile C[256bi.., 256bj..].
// Thread (wave w, lane l; gg=l>>3, c8=l&7) owns rows r0=32w+4gg..+4 and
// cols {32cc+4c8+e}, i.e. creg[4][32] with col index i = 4cc+e.
//
// Per iteration:
//  u-phase: row-LSE over my 256 local cols (8-lane shfl) -> post 1KB row
//    partials to rp -> wait 8 row-band peers -> merge 8 partials/row -> U.
//  v-phase: col-partials over my 4 rows -> wave shfl merge (gg) -> LDS
//    merge (8 waves) -> post 1KB col partials to cp -> wait 8 col-band
//    peers -> merge -> V.
// Fan-in per hop: 8 (vs 64 in the 1D layout); no dedicated reduce stage,
// no V broadcast. rp/cp are parity double-buffered: posting epoch k+1
// implies the poster finished READING epoch k (program order), and I only
// post epoch k+2 after observing all epoch-k+1 posts -> reuse is race-free.
// ---------------------------------------------------------------------------
__global__ __launch_bounds__(TPB, 2) void sinkhorn_all(
    const float* __restrict__ x, const float* __restrict__ y,
    float* __restrict__ Cout, float* __restrict__ pi,
    float* __restrict__ cost, float* __restrict__ rp,
    float* __restrict__ cp, unsigned* __restrict__ flags, float l2mu) {
  __shared__ SMem sm;
  const int t = threadIdx.x;
  const int w = t >> 6;
  const int l = t & 63;
  const int gg = l >> 3;
  const int c8 = l & 7;
  const int b = blockIdx.x;
  const int n = b >> 6;
  const int bi = (b >> 3) & 7;
  const int bj = b & 7;
  const size_t xyb = (size_t)n * P * DF;
  const size_t cb = (size_t)n * P * P;
  const int r0 = 32 * w + 4 * gg;  // local row base (4 rows)
  unsigned* rowflag = flags + (n * 8 + bi) * 8;        // [8] row-band stamps
  unsigned* colflag = flags + 256 + (n * 8 + bj) * 8;  // [8] col-band stamps
  unsigned* ef = flags + 512;                          // [256] epilogue rendezvous

  float creg[4][32];  // C * INV_EPS * log2e, [row r][i=4cc+e]

  // ---------------- build phase (two 32-d halves; x,y tiles staged) --------
#pragma unroll
  for (int r = 0; r < 4; ++r)
#pragma unroll
    for (int i = 0; i < 32; ++i) creg[r][i] = 0.f;

  const int cl = t >> 1;        // staging row 0..255
  const int db = (t & 1) * 16;  // staging d-offset within half
#pragma unroll
  for (int h = 0; h < 2; ++h) {
    __syncthreads();  // protect previous half's tiles
    {
      const float* xp = x + xyb + (size_t)(TS * bi + cl) * DF + 32 * h + db;
      float4 q0 = *(const float4*)(xp + 0);
      float4 q1 = *(const float4*)(xp + 4);
      float4 q2 = *(const float4*)(xp + 8);
      float4 q3 = *(const float4*)(xp + 12);
      float* xs = sm.b.xs;
      xs[(db + 0) * 260 + cl] = q0.x;  xs[(db + 1) * 260 + cl] = q0.y;
      xs[(db + 2) * 260 + cl] = q0.z;  xs[(db + 3) * 260 + cl] = q0.w;
      xs[(db + 4) * 260 + cl] = q1.x;  xs[(db + 5) * 260 + cl] = q1.y;
      xs[(db + 6) * 260 + cl] = q1.z;  xs[(db + 7) * 260 + cl] = q1.w;
      xs[(db + 8) * 260 + cl] = q2.x;  xs[(db + 9) * 260 + cl] = q2.y;
      xs[(db + 10) * 260 + cl] = q2.z; xs[(db + 11) * 260 + cl] = q2.w;
      xs[(db + 12) * 260 + cl] = q3.x; xs[(db + 13) * 260 + cl] = q3.y;
      xs[(db + 14) * 260 + cl] = q3.z; xs[(db + 15) * 260 + cl] = q3.w;
      const float* yp = y + xyb + (size_t)(TS * bj + cl) * DF + 32 * h + db;
      q0 = *(const float4*)(yp + 0);
      q1 = *(const float4*)(yp + 4);
      q2 = *(const float4*)(yp + 8);
      q3 = *(const float4*)(yp + 12);
      float* ys = sm.b.ys;
      ys[(db + 0) * 260 + cl] = q0.x;  ys[(db + 1) * 260 + cl] = q0.y;
      ys[(db + 2) * 260 + cl] = q0.z;  ys[(db + 3) * 260 + cl] = q0.w;
      ys[(db + 4) * 260 + cl] = q1.x;  ys[(db + 5) * 260 + cl] = q1.y;
      ys[(db + 6) * 260 + cl] = q1.z;  ys[(db + 7) * 260 + cl] = q1.w;
      ys[(db + 8) * 260 + cl] = q2.x;  ys[(db + 9) * 260 + cl] = q2.y;
      ys[(db + 10) * 260 + cl] = q2.z; ys[(db + 11) * 260 + cl] = q2.w;
      ys[(db + 12) * 260 + cl] = q3.x; ys[(db + 13) * 260 + cl] = q3.y;
      ys[(db + 14) * 260 + cl] = q3.z; ys[(db + 15) * 260 + cl] = q3.w;
    }
    __syncthreads();
#pragma unroll 4
    for (int dd = 0; dd < 32; ++dd) {
      float4 x4 = *(const float4*)&sm.b.xs[dd * 260 + r0];
      float xv[4] = {x4.x, x4.y, x4.z, x4.w};
#pragma unroll
      for (int cc = 0; cc < 8; ++cc) {
        float4 y4 = *(const float4*)&sm.b.ys[dd * 260 + 32 * cc + 4 * c8];
        float yv[4] = {y4.x, y4.y, y4.z, y4.w};
#pragma unroll
        for (int r = 0; r < 4; ++r)
#pragma unroll
          for (int e = 0; e < 4; ++e) {
            float dfv = xv[r] - yv[e];
            creg[r][4 * cc + e] = fmaf(dfv, dfv, creg[r][4 * cc + e]);
          }
      }
    }
  }
  // store C (raw), then scale creg in place
#pragma unroll
  for (int r = 0; r < 4; ++r) {
    const size_t rowb = cb + (size_t)(TS * bi + r0 + r) * P + TS * bj;
#pragma unroll
    for (int cc = 0; cc < 8; ++cc) {
      vfloat4 c4 = {creg[r][4 * cc + 0], creg[r][4 * cc + 1],
                    creg[r][4 * cc + 2], creg[r][4 * cc + 3]};
      __builtin_nontemporal_store(c4, (vfloat4*)(Cout + rowb + 32 * cc + 4 * c8));
      creg[r][4 * cc + 0] *= SCALE;
      creg[r][4 * cc + 1] *= SCALE;
      creg[r][4 * cc + 2] *= SCALE;
      creg[r][4 * cc + 3] *= SCALE;
    }
  }
  __syncthreads();  // build->iter LDS union hazard

  // ---------------- 50 Sinkhorn iterations (scaled base-2 log domain) ------
  float U[4];
  float vreg[32];  // V for my cols, i = 4cc+e <-> local col 32cc+4c8+e
#pragma unroll
  for (int i = 0; i < 32; ++i) vreg[i] = 0.f;

#pragma unroll 1
  for (int it = 0; it < MAX_ITER; ++it) {
    float* rpp = rp + (it & 1) * PARF;
    float* cpp = cp + (it & 1) * PARF;
    // ---- u-phase: row partials over my 256 local cols ----
    float Lrow[4];
#pragma unroll
    for (int r = 0; r < 4; ++r) {
      float arg[32];
      float m = -3.4e38f;
#pragma unroll
      for (int i = 0; i < 32; ++i) {
        arg[i] = vreg[i] - creg[r][i];
        m = fmaxf(m, arg[i]);
      }
      m = fmaxf(m, __shfl_xor(m, 1));
      m = fmaxf(m, __shfl_xor(m, 2));
      m = fmaxf(m, __shfl_xor(m, 4));
      float s = 0.f;
#pragma unroll
      for (int i = 0; i < 32; ++i) s += EXP2(arg[i] - m);
      s += __shfl_xor(s, 1);
      s += __shfl_xor(s, 2);
      s += __shfl_xor(s, 4);
      Lrow[r] = m + LOG2(s);
    }
    if (c8 == 0) {  // 64 posting threads, 4 consecutive rows each
      float* dst = rpp + ((n * 8 + bi) * 8 + bj) * TS + r0;
      store_f2_agent(dst, Lrow[0], Lrow[1]);
      store_f2_agent(dst + 2, Lrow[2], Lrow[3]);
    }
    __threadfence_block();  // vmcnt drain: retired sc1 stores visible
    __syncthreads();
    if (t == 0) flag_store(&rowflag[bj], (unsigned)(it + 1));
    if (t < 8) {
      while (flag_load(&rowflag[t]) < (unsigned)(it + 1)) __builtin_amdgcn_s_sleep(1);
    }
    __syncthreads();
    {  // stage 8 peers' row partials (2048 floats contiguous)
      const float* src = rpp + (n * 8 + bi) * 8 * TS + 4 * t;
      float2 a = load_f2_agent(src);
      float2 b2 = load_f2_agent(src + 2);
      vfloat4 vv = {a.x, a.y, b2.x, b2.y};
      *(vfloat4*)&sm.c.rin[(t >> 6) * 260 + (t & 63) * 4] = vv;
    }
    __syncthreads();
    if (t < TS) {  // merge 8 partials per row -> U
      float m = sm.c.rin[t];
#pragma unroll
      for (int p = 1; p < 8; ++p) m = fmaxf(m, sm.c.rin[p * 260 + t]);
      float s = 0.f;
#pragma unroll
      for (int p = 0; p < 8; ++p) s += EXP2(sm.c.rin[p * 260 + t] - m);
      sm.c.red[t] = l2mu - (m + LOG2(s));
    }
    __syncthreads();
#pragma unroll
    for (int r = 0; r < 4; ++r) U[r] = sm.c.red[r0 + r];

    // ---- v-phase: col partials over my 256 local rows ----
    float cm[32], cs_[32];
#pragma unroll
    for (int i = 0; i < 32; ++i) {
      float a0 = U[0] - creg[0][i];
      float a1 = U[1] - creg[1][i];
      float a2 = U[2] - creg[2][i];
      float a3 = U[3] - creg[3][i];
      float m = fmaxf(fmaxf(a0, a1), fmaxf(a2, a3));
      cm[i] = m;
      cs_[i] = EXP2(a0 - m) + EXP2(a1 - m) + EXP2(a2 - m) + EXP2(a3 - m);
    }
#pragma unroll
    for (int step = 8; step <= 32; step <<= 1) {  // merge 8 gg groups
#pragma unroll
      for (int i = 0; i < 32; ++i) {
        float mo = __shfl_xor(cm[i], step);
        float so = __shfl_xor(cs_[i], step);
        lse_merge(cm[i], cs_[i], mo, so);
      }
    }
    if (gg == 0) {  // 8 lanes/wave dump wave col-partials as L
#pragma unroll
      for (int i = 0; i < 32; ++i)
        sm.c.cw[w * 260 + 32 * (i >> 2) + 4 * c8 + (i & 3)] = cm[i] + LOG2(cs_[i]);
    }
    __syncthreads();
    if (t < TS) {  // merge 8 waves, post col partial (coalesced 1KB)
      float m = sm.c.cw[t];
#pragma unroll
      for (int wv = 1; wv < 8; ++wv) m = fmaxf(m, sm.c.cw[wv * 260 + t]);
      float s = 0.f;
#pragma unroll
      for (int wv = 0; wv < 8; ++wv) s += EXP2(sm.c.cw[wv * 260 + t] - m);
      store_f_agent(cpp + ((n * 8 + bj) * 8 + bi) * TS + t, m + LOG2(s));
    }
    __threadfence_block();
    __syncthreads();
    if (t == 0) flag_store(&colflag[bi], (unsigned)(it + 1));
    if (t < 8) {
      while (flag_load(&colflag[t]) < (unsigned)(it + 1)) __builtin_amdgcn_s_sleep(1);
    }
    __syncthreads();
    {  // stage 8 peers' col partials
      const float* src = cpp + (n * 8 + bj) * 8 * TS + 4 * t;
      float2 a = load_f2_agent(src);
      float2 b2 = load_f2_agent(src + 2);
      vfloat4 vv = {a.x, a.y, b2.x, b2.y};
      *(vfloat4*)&sm.c.rin[(t >> 6) * 260 + (t & 63) * 4] = vv;
    }
    __syncthreads();
    if (t < TS) {  // merge 8 partials per col -> V
      float m = sm.c.rin[t];
#pragma unroll
      for (int p = 1; p < 8; ++p) m = fmaxf(m, sm.c.rin[p * 260 + t]);
      float s = 0.f;
#pragma unroll
      for (int p = 0; p < 8; ++p) s += EXP2(sm.c.rin[p * 260 + t] - m);
      sm.c.red[t] = l2mu - (m + LOG2(s));
    }
    __syncthreads();
#pragma unroll
    for (int i = 0; i < 32; ++i)
      vreg[i] = sm.c.red[32 * (i >> 2) + 4 * c8 + (i & 3)];
    __syncthreads();  // red consumed before next iteration overwrites
  }
  // here: U = U(50), vreg = V(50)

  // ---------------- epilogue: pi and cost ----------------
  // rp/cp live inside the pi region: GLOBAL rendezvous before overwrite.
  // (last cp reads were consumed into LDS -> waitcnt'd before the final
  // barriers above, so stamping now is safe)
  if (t == 0) flag_store(&ef[b], 1u);
  if (t < 256) {
    while (flag_load(&ef[t]) < 1u) __builtin_amdgcn_s_sleep(1);
  }
  __syncthreads();
  float csum = 0.f;
#pragma unroll
  for (int r = 0; r < 4; ++r) {
    const size_t rowb = cb + (size_t)(TS * bi + r0 + r) * P + TS * bj;
#pragma unroll
    for (int cc = 0; cc < 8; ++cc) {
      vfloat4 p4;
      p4.x = EXP2(U[r] + vreg[4 * cc + 0] - creg[r][4 * cc + 0]);
      p4.y = EXP2(U[r] + vreg[4 * cc + 1] - creg[r][4 * cc + 1]);
      p4.z = EXP2(U[r] + vreg[4 * cc + 2] - creg[r][4 * cc + 2]);
      p4.w = EXP2(U[r] + vreg[4 * cc + 3] - creg[r][4 * cc + 3]);
      csum += p4.x * creg[r][4 * cc + 0] + p4.y * creg[r][4 * cc + 1]
            + p4.z * creg[r][4 * cc + 2] + p4.w * creg[r][4 * cc + 3];
      __builtin_nontemporal_store(p4, (vfloat4*)(pi + rowb + 32 * cc + 4 * c8));
    }
  }
  float cs = csum * C2N;  // creg = C*INV_EPS*log2e -> sum(pi*creg)*EPS*ln2
#pragma unroll
  for (int off = 32; off; off >>= 1) cs += __shfl_xor(cs, off);
  if (l == 0) atomicAdd(cost + n, cs);
}

// ===========================================================================
// Fallback path (round-1 kernels, known-good) in case cooperative launch fails
// ===========================================================================
__global__ __launch_bounds__(256) void build_c(const float* __restrict__ x,
                                               const float* __restrict__ y,
                                               float* __restrict__ C,
                                               float* __restrict__ CT) {
  __shared__ float xs[DF][68];
  __shared__ float ys[DF][68];
  const int n = blockIdx.z;
  const int i0 = blockIdx.y * 64, j0 = blockIdx.x * 64;
  const int t = threadIdx.x;
  const int lr = t >> 4, c4 = (t & 15) * 4;
  const size_t xb = (size_t)n * P * DF;
  for (int rr = lr; rr < 64; rr += 16) {
    float4 xv = *(const float4*)(x + xb + (size_t)(i0 + rr) * DF + c4);
    float4 yv = *(const float4*)(y + xb + (size_t)(j0 + rr) * DF + c4);
    xs[c4 + 0][rr] = xv.x; xs[c4 + 1][rr] = xv.y;
    xs[c4 + 2][rr] = xv.z; xs[c4 + 3][rr] = xv.w;
    ys[c4 + 0][rr] = yv.x; ys[c4 + 1][rr] = yv.y;
    ys[c4 + 2][rr] = yv.z; ys[c4 + 3][rr] = yv.w;
  }
  __syncthreads();
  const int ty = t >> 4, tx = t & 15;
  float acc[4][4];
#pragma unroll
  for (int e = 0; e < 4; ++e)
#pragma unroll
    for (int f = 0; f < 4; ++f) acc[e][f] = 0.f;
#pragma unroll 4
  for (int d = 0; d < DF; ++d) {
    float4 a4 = *(const float4*)&xs[d][4 * ty];
    float4 b4 = *(const float4*)&ys[d][4 * tx];
    float av[4] = {a4.x, a4.y, a4.z, a4.w};
    float bv[4] = {b4.x, b4.y, b4.z, b4.w};
#pragma unroll
    for (int e = 0; e < 4; ++e)
#pragma unroll
      for (int f = 0; f < 4; ++f) {
        float df = av[e] - bv[f];
        acc[e][f] = fmaf(df, df, acc[e][f]);
      }
  }
  const size_t cbase = (size_t)n * P * P;
#pragma unroll
  for (int e = 0; e < 4; ++e) {
    float4 v4 = make_float4(acc[e][0], acc[e][1], acc[e][2], acc[e][3]);
    *(float4*)(C + cbase + (size_t)(i0 + 4 * ty + e) * P + (j0 + 4 * tx)) = v4;
  }
#pragma unroll
  for (int f = 0; f < 4; ++f) {
    float4 v4 = make_float4(acc[0][f], acc[1][f], acc[2][f], acc[3][f]);
    *(float4*)(CT + cbase + (size_t)(j0 + 4 * tx + f) * P + (i0 + 4 * ty)) = v4;
  }
}

__global__ __launch_bounds__(256) void lse_pass(const float* __restrict__ M,
                                                const float* __restrict__ wv_,
                                                float* __restrict__ out,
                                                float log_w) {
  __shared__ float red[8];
  const int b = blockIdx.x;
  const int n = b >> 11;
  const int t = threadIdx.x;
  const float4* row = (const float4*)(M + (size_t)b * P);
  const float4* wv = (const float4*)(wv_ + (size_t)n * P);
  float4 c0 = row[t], c1 = row[t + 256];
  float4 w0 = wv[t], w1 = wv[t + 256];
  float a[8];
  a[0] = (w0.x - c0.x) * INV_EPS; a[1] = (w0.y - c0.y) * INV_EPS;
  a[2] = (w0.z - c0.z) * INV_EPS; a[3] = (w0.w - c0.w) * INV_EPS;
  a[4] = (w1.x - c1.x) * INV_EPS; a[5] = (w1.y - c1.y) * INV_EPS;
  a[6] = (w1.z - c1.z) * INV_EPS; a[7] = (w1.w - c1.w) * INV_EPS;
  float mx = a[0];
#pragma unroll
  for (int k = 1; k < 8; ++k) mx = fmaxf(mx, a[k]);
#pragma unroll
  for (int o = 32; o > 0; o >>= 1) mx = fmaxf(mx, __shfl_xor(mx, o));
  if ((t & 63) == 0) red[t >> 6] = mx;
  __syncthreads();
  mx = fmaxf(fmaxf(red[0], red[1]), fmaxf(red[2], red[3]));
  float s = 0.f;
#pragma unroll
  for (int k = 0; k < 8; ++k) s += __expf(a[k] - mx);
#pragma unroll
  for (int o = 32; o > 0; o >>= 1) s += __shfl_xor(s, o);
  if ((t & 63) == 0) red[4 + (t >> 6)] = s;
  __syncthreads();
  if (t == 0) {
    float S = red[4] + red[5] + red[6] + red[7];
    out[b] = EPS * (log_w - (mx + __logf(S)));
  }
}

__global__ __launch_bounds__(256) void final_pass(const float* __restrict__ C,
                                                  const float* __restrict__ u,
                                                  const float* __restrict__ v,
                                                  float* __restrict__ pi,
                                                  float* __restrict__ cost) {
  __shared__ float red[4];
  const int b = blockIdx.x;
  const int n = b >> 11;
  const int t = threadIdx.x;
  const float ui = u[b];
  const float4* row = (const float4*)(C + (size_t)b * P);
  const float4* vv = (const float4*)(v + (size_t)n * P);
  float4* prow = (float4*)(pi + (size_t)b * P);
  float local = 0.f;
#pragma unroll
  for (int h = 0; h < 2; ++h) {
    float4 c = row[t + 256 * h];
    float4 vw = vv[t + 256 * h];
    float4 p;
    p.x = __expf((ui + vw.x - c.x) * INV_EPS);
    p.y = __expf((ui + vw.y - c.y) * INV_EPS);
    p.z = __expf((ui + vw.z - c.z) * INV_EPS);
    p.w = __expf((ui + vw.w - c.w) * INV_EPS);
    prow[t + 256 * h] = p;
    local += p.x * c.x + p.y * c.y + p.z * c.z + p.w * c.w;
  }
#pragma unroll
  for (int o = 32; o > 0; o >>= 1) local += __shfl_xor(local, o);
  if ((t & 63) == 0) red[t >> 6] = local;
  __syncthreads();
  if (t == 0) {
    float S = red[0] + red[1] + red[2] + red[3];
    atomicAdd(cost + n, S);
  }
}

extern "C" void kernel_launch(void* const* d_in, const int* in_sizes, int n_in,
                              void* d_out, int out_size, void* d_ws, size_t ws_size,
                              hipStream_t stream) {
  const float* x = (const float*)d_in[0];
  const float* y = (const float*)d_in[1];
  float* cost = (float*)d_out;                 // 4 floats
  float* pi = cost + 4;                        // 4*2048*2048
  float* C = pi + (size_t)NB * P * P;          // 4*2048*2048
  // scratch carved out of the pi output slot (fully overwritten by epilogue):
  float* rp = pi;                    // [2][4][8][8][256] row partials (512 KB)
  float* cp = pi + 2 * PARF;         // [2][4][8][8][256] col partials (512 KB)
  unsigned* flags = (unsigned*)d_ws; // rowflag[256] + colflag[256] + ef[256]

  (void)hipMemsetAsync(cost, 0, NB * sizeof(float), stream);
  (void)hipMemsetAsync(flags, 0, 4096, stream);

  float lmu = logf(1.0f / (float)P + 1e-8f);    // nat log (fallback)
  float l2mu = log2f(1.0f / (float)P + 1e-8f);  // base-2 log (main)

  void* args[] = {(void*)&x, (void*)&y, (void*)&C, (void*)&pi,
                  (void*)&cost, (void*)&rp, (void*)&cp, (void*)&flags,
                  (void*)&l2mu};
  hipError_t err = hipLaunchCooperativeKernel((void*)sinkhorn_all, dim3(NBLK),
                                              dim3(TPB), args, 0, stream);
  if (err != hipSuccess) {
    // fallback: round-1 multi-kernel path (deterministically taken if coop fails)
    float* u = (float*)d_ws;
    float* v = u + NB * P;
    (void)hipMemsetAsync(v, 0, NB * P * sizeof(float), stream);
    float* CT = pi;
    build_c<<<dim3(32, 32, 4), 256, 0, stream>>>(x, y, C, CT);
    for (int it = 0; it < MAX_ITER; ++it) {
      lse_pass<<<NB * P, 256, 0, stream>>>(C, v, u, lmu);
      lse_pass<<<NB * P, 256, 0, stream>>>(CT, u, v, lmu);
    }
    final_pass<<<NB * P, 256, 0, stream>>>(C, u, v, pi, cost);
  }
}

// Round 6
// 856.095 us; speedup vs baseline: 1.3485x; 1.3485x over previous
//
#include <hip/hip_runtime.h>
#include <math.h>

#define NB 4
#define P 2048
#define DF 64
#define EPS 0.1f
#define INV_EPS 10.0f
#define MAX_ITER 50
#define NBLK 256   // 1 block per CU (cooperative, co-resident)
#define TPB 512    // 8 waves
#define TR 128     // tile rows  (per chain)
#define TC 256     // tile cols  (per chain)
// base-2 log domain: creg = C * INV_EPS * log2(e); cost = sum(pi*creg)*EPS*ln2
#define SCALE 14.426950408889634f
#define C2N 0.069314718055994531f
#define RPF (NB * P * 8)    // row-partial floats per parity buffer (65536)
#define CPF (NB * P * 16)   // col-partial floats per parity buffer (131072)

typedef float vfloat4 __attribute__((ext_vector_type(4)));  // native vec for nt-store

#if __has_builtin(__builtin_amdgcn_exp2f)
#define EXP2(x) __builtin_amdgcn_exp2f(x)
#else
#define EXP2(x) exp2f(x)
#endif
#if __has_builtin(__builtin_amdgcn_logf)
#define LOG2(x) __builtin_amdgcn_logf(x)
#else
#define LOG2(x) log2f(x)
#endif

struct BuildMem { float xs[32 * 132]; float ys[32 * 260]; };  // 16.9 + 33.3 KB
union IterBuf {
  float rin[8 * 132];    // row-partial staging (4.2 KB)
  float Ld[64 * 260];    // within-block col-partial dump (66.6 KB)
  float cin[16 * 260];   // col-partial staging (16.6 KB)
};
struct SMem {
  union { BuildMem b; IterBuf ib; } u;  // 66.6 KB
  float red[132];                       // row-merge output (U values)
  float vlds[2][260];                   // per-chain V (persists across stages)
};                                      // total ~69.2 KB

// ---------------------------------------------------------------------------
// Agent-coherent (L2-bypassing) data movement. Relaxed atomics at AGENT
// scope. Visibility protocol (HW-verified rounds 0-5):
//   writer: stores -> __threadfence_block+__syncthreads (vmcnt drain) ->
//           t0 stamps flag (plain agent store)
//   reader: poll flags in PARALLEL -> __syncthreads -> agent data loads
// ---------------------------------------------------------------------------
__device__ __forceinline__ void flag_store(unsigned* f, unsigned v) {
  __hip_atomic_store(f, v, __ATOMIC_RELAXED, __HIP_MEMORY_SCOPE_AGENT);
}
__device__ __forceinline__ unsigned flag_load(unsigned* f) {
  return __hip_atomic_load(f, __ATOMIC_RELAXED, __HIP_MEMORY_SCOPE_AGENT);
}
__device__ __forceinline__ void store_f2_agent(float* p, float a, float b) {
  unsigned long long bits =
      ((unsigned long long)__float_as_uint(b) << 32) | __float_as_uint(a);
  __hip_atomic_store((unsigned long long*)p, bits, __ATOMIC_RELAXED,
                     __HIP_MEMORY_SCOPE_AGENT);
}
__device__ __forceinline__ float2 load_f2_agent(const float* p) {
  unsigned long long bits = __hip_atomic_load((unsigned long long*)p,
      __ATOMIC_RELAXED, __HIP_MEMORY_SCOPE_AGENT);
  return make_float2(__uint_as_float((unsigned)bits),
                     __uint_as_float((unsigned)(bits >> 32)));
}
__device__ __forceinline__ void store_f_agent(float* p, float v) {
  __hip_atomic_store(p, v, __ATOMIC_RELAXED, __HIP_MEMORY_SCOPE_AGENT);
}

// ---------------------------------------------------------------------------
// Dual-chain 2D tiling. Block b: g = b>>7 (batch pair), idx = b&127,
// ti = idx>>3 (16 row-tiles), tj = idx&7 (8 col-tiles). Chains A/B = batches
// 2g/2g+1, each a 128x256 tile. Thread (w, l; gg=l>>3, c8=l&7) owns rows
// r0=16w+2gg..+1 and cols {32cc+4c8+e} -> creg[chain][2][32].
//
// Stage schedule per iteration k (anti-phased chains => every flag wait is
// buffered by >=1.5 compute stages of the OTHER chain):
//   rowMerge_A(k) vA(k) rowMerge_B(k) vB(k)
//   colMerge_A(k) uA(k+1) colMerge_B(k) uB(k+1)
// Parity-2 buffers: posting stamp s+2 happens after my row-wait of stamp
// s+1, which proves every peer posted s+1, which (by their program order)
// proves they finished reading stamp s -> overwrite is race-free.
// ---------------------------------------------------------------------------
__device__ __forceinline__ void u_stage(
    int k, int t, int c8, int r0, int ti, int tj, int n,
    const float (&cr)[2][32], const float* vl,
    float* rpp, unsigned* rf_mine) {
  float vv[32];
#pragma unroll
  for (int i = 0; i < 32; ++i) vv[i] = vl[32 * (i >> 2) + 4 * c8 + (i & 3)];
  float Lr[2];
#pragma unroll
  for (int r = 0; r < 2; ++r) {
    float m = -3.4e38f;
#pragma unroll
    for (int i = 0; i < 32; ++i) m = fmaxf(m, vv[i] - cr[r][i]);
    m = fmaxf(m, __shfl_xor(m, 1));
    m = fmaxf(m, __shfl_xor(m, 2));
    m = fmaxf(m, __shfl_xor(m, 4));
    float s = 0.f;
#pragma unroll
    for (int i = 0; i < 32; ++i) s += EXP2(vv[i] - cr[r][i] - m);
    s += __shfl_xor(s, 1);
    s += __shfl_xor(s, 2);
    s += __shfl_xor(s, 4);
    Lr[r] = m + LOG2(s);
  }
  if (c8 == 0)  // 64 threads x 2 rows = 128 row partials, coalesced pairs
    store_f2_agent(rpp + ((n * 16 + ti) * 8 + tj) * TR + r0, Lr[0], Lr[1]);
  __threadfence_block();  // vmcnt drain: retired agent stores visible
  __syncthreads();
  if (t == 0) flag_store(rf_mine, (unsigned)(k + 1));
}

__device__ __forceinline__ void row_merge(
    int k, int t, int r0, int ti, int n,
    float (&Ucr)[2], const float* rpp, unsigned* rfb, SMem& sm, float l2mu) {
  if (t < 8) {
    while (flag_load(rfb + t) < (unsigned)(k + 1)) __builtin_amdgcn_s_sleep(1);
  }
  __syncthreads();
  {  // stage 8 peers x 128 rows = 1024 contiguous floats
    const int idx = 2 * t;
    float2 a = load_f2_agent(rpp + (n * 16 + ti) * 1024 + idx);
    const int j = idx >> 7, row = idx & 127;
    *(float2*)&sm.u.ib.rin[j * 132 + row] = a;
  }
  __syncthreads();
  if (t < 128) {  // merge 8 partials per row -> U
    float m = sm.u.ib.rin[t];
#pragma unroll
    for (int j = 1; j < 8; ++j) m = fmaxf(m, sm.u.ib.rin[j * 132 + t]);
    float s = 0.f;
#pragma unroll
    for (int j = 0; j < 8; ++j) s += EXP2(sm.u.ib.rin[j * 132 + t] - m);
    sm.red[t] = l2mu - (m + LOG2(s));
  }
  __syncthreads();
  Ucr[0] = sm.red[r0];      // 8-lane broadcast reads
  Ucr[1] = sm.red[r0 + 1];
}

__device__ __forceinline__ void v_stage(
    int k, int t, int w, int gg, int c8, int ti, int tj, int n,
    const float (&cr)[2][32], const float (&Ucr)[2],
    float* cpp, unsigned* cf_mine, SMem& sm) {
  const int grp = 8 * w + gg;  // 64 row-groups of 2 rows
#pragma unroll
  for (int i = 0; i < 32; ++i) {
    float a0 = Ucr[0] - cr[0][i];
    float a1 = Ucr[1] - cr[1][i];
    float pm = fmaxf(a0, a1);
    float ps = 1.f + EXP2(-fabsf(a0 - a1));  // 2-row LSE: one exp2
    sm.u.ib.Ld[grp * 260 + 32 * (i >> 2) + 4 * c8 + (i & 3)] = pm + LOG2(ps);
  }
  __syncthreads();
  if (t < TC) {  // merge 64 groups per col, post (coalesced 1KB)
    float m = sm.u.ib.Ld[t];
#pragma unroll
    for (int g2 = 1; g2 < 64; ++g2) m = fmaxf(m, sm.u.ib.Ld[g2 * 260 + t]);
    float s = 0.f;
#pragma unroll
    for (int g2 = 0; g2 < 64; ++g2) s += EXP2(sm.u.ib.Ld[g2 * 260 + t] - m);
    store_f_agent(cpp + ((n * 8 + tj) * 16 + ti) * TC + t, m + LOG2(s));
  }
  __threadfence_block();
  __syncthreads();
  if (t == 0) flag_store(cf_mine, (unsigned)(k + 1));
}

__device__ __forceinline__ void col_merge(
    int k, int t, int tj, int n, float* vl,
    const float* cpp, unsigned* cfb, SMem& sm, float l2mu) {
  if (t < 16) {
    while (flag_load(cfb + t) < (unsigned)(k + 1)) __builtin_amdgcn_s_sleep(1);
  }
  __syncthreads();
  {  // stage 16 peers x 256 cols = 4096 contiguous floats
    const int idx = 8 * t;
    const int jj = idx >> 8, col = idx & 255;
    const float* src = cpp + (n * 8 + tj) * 4096 + idx;
    float2 a = load_f2_agent(src);
    float2 b2 = load_f2_agent(src + 2);
    float2 c2 = load_f2_agent(src + 4);
    float2 d2 = load_f2_agent(src + 6);
    vfloat4 v0 = {a.x, a.y, b2.x, b2.y};
    vfloat4 v1 = {c2.x, c2.y, d2.x, d2.y};
    *(vfloat4*)&sm.u.ib.cin[jj * 260 + col] = v0;
    *(vfloat4*)&sm.u.ib.cin[jj * 260 + col + 4] = v1;
  }
  __syncthreads();
  if (t < TC) {  // merge 16 partials per col -> V (into persistent LDS)
    float m = sm.u.ib.cin[t];
#pragma unroll
    for (int j = 1; j < 16; ++j) m = fmaxf(m, sm.u.ib.cin[j * 260 + t]);
    float s = 0.f;
#pragma unroll
    for (int j = 0; j < 16; ++j) s += EXP2(sm.u.ib.cin[j * 260 + t] - m);
    vl[t] = l2mu - (m + LOG2(s));
  }
  __syncthreads();
}

__global__ __launch_bounds__(TPB, 2) void sinkhorn_all(
    const float* __restrict__ x, const float* __restrict__ y,
    float* __restrict__ Cout, float* __restrict__ pi,
    float* __restrict__ cost, float* __restrict__ rp,
    float* __restrict__ cp, unsigned* __restrict__ flags, float l2mu) {
  __shared__ SMem sm;
  const int t = threadIdx.x;
  const int w = t >> 6;
  const int l = t & 63;
  const int gg = l >> 3;
  const int c8 = l & 7;
  const int b = blockIdx.x;
  const int g = b >> 7;
  const int idx = b & 127;
  const int ti = idx >> 3;
  const int tj = idx & 7;
  const int nA = 2 * g, nB = 2 * g + 1;
  const int r0 = 16 * w + 2 * gg;
  unsigned* rfA_mine = flags + (nA * 16 + ti) * 8 + tj;
  unsigned* rfB_mine = flags + (nB * 16 + ti) * 8 + tj;
  unsigned* rfA_band = flags + (nA * 16 + ti) * 8;
  unsigned* rfB_band = flags + (nB * 16 + ti) * 8;
  unsigned* cfA_mine = flags + 512 + (nA * 8 + tj) * 16 + ti;
  unsigned* cfB_mine = flags + 512 + (nB * 8 + tj) * 16 + ti;
  unsigned* cfA_band = flags + 512 + (nA * 8 + tj) * 16;
  unsigned* cfB_band = flags + 512 + (nB * 8 + tj) * 16;
  unsigned* ef = flags + 1024;

  float creg[2][2][32];  // [chain][row][col], C * INV_EPS * log2e
  float U[2][2];

  // ---------------- build phase (both chains) ----------------
#pragma unroll
  for (int c = 0; c < 2; ++c) {
    const int n = 2 * g + c;
    const size_t xyb = (size_t)n * P * DF;
#pragma unroll
    for (int r = 0; r < 2; ++r)
#pragma unroll
      for (int i = 0; i < 32; ++i) creg[c][r][i] = 0.f;
#pragma unroll
    for (int h = 0; h < 2; ++h) {
      __syncthreads();  // protect previous tiles
      {  // stage x tile: 128 rows x 32 d (transposed)
        const int cl = t >> 2, db = (t & 3) * 8;
        const float* xp = x + xyb + (size_t)(TR * ti + cl) * DF + 32 * h + db;
        float4 q0 = *(const float4*)(xp);
        float4 q1 = *(const float4*)(xp + 4);
        float* xs = sm.u.b.xs;
        xs[(db + 0) * 132 + cl] = q0.x; xs[(db + 1) * 132 + cl] = q0.y;
        xs[(db + 2) * 132 + cl] = q0.z; xs[(db + 3) * 132 + cl] = q0.w;
        xs[(db + 4) * 132 + cl] = q1.x; xs[(db + 5) * 132 + cl] = q1.y;
        xs[(db + 6) * 132 + cl] = q1.z; xs[(db + 7) * 132 + cl] = q1.w;
      }
      {  // stage y tile: 256 rows x 32 d (transposed)
        const int cl = t >> 1, db = (t & 1) * 16;
        const float* yp = y + xyb + (size_t)(TC * tj + cl) * DF + 32 * h + db;
        float4 q0 = *(const float4*)(yp + 0);
        float4 q1 = *(const float4*)(yp + 4);
        float4 q2 = *(const float4*)(yp + 8);
        float4 q3 = *(const float4*)(yp + 12);
        float* ys = sm.u.b.ys;
        ys[(db + 0) * 260 + cl] = q0.x;  ys[(db + 1) * 260 + cl] = q0.y;
        ys[(db + 2) * 260 + cl] = q0.z;  ys[(db + 3) * 260 + cl] = q0.w;
        ys[(db + 4) * 260 + cl] = q1.x;  ys[(db + 5) * 260 + cl] = q1.y;
        ys[(db + 6) * 260 + cl] = q1.z;  ys[(db + 7) * 260 + cl] = q1.w;
        ys[(db + 8) * 260 + cl] = q2.x;  ys[(db + 9) * 260 + cl] = q2.y;
        ys[(db + 10) * 260 + cl] = q2.z; ys[(db + 11) * 260 + cl] = q2.w;
        ys[(db + 12) * 260 + cl] = q3.x; ys[(db + 13) * 260 + cl] = q3.y;
        ys[(db + 14) * 260 + cl] = q3.z; ys[(db + 15) * 260 + cl] = q3.w;
      }
      __syncthreads();
#pragma unroll 4
      for (int dd = 0; dd < 32; ++dd) {
        float2 x2 = *(const float2*)&sm.u.b.xs[dd * 132 + r0];
#pragma unroll
        for (int cc = 0; cc < 8; ++cc) {
          float4 y4 = *(const float4*)&sm.u.b.ys[dd * 260 + 32 * cc + 4 * c8];
          float d0, d1;
          d0 = x2.x - y4.x; creg[c][0][4*cc+0] = fmaf(d0, d0, creg[c][0][4*cc+0]);
          d1 = x2.y - y4.x; creg[c][1][4*cc+0] = fmaf(d1, d1, creg[c][1][4*cc+0]);
          d0 = x2.x - y4.y; creg[c][0][4*cc+1] = fmaf(d0, d0, creg[c][0][4*cc+1]);
          d1 = x2.y - y4.y; creg[c][1][4*cc+1] = fmaf(d1, d1, creg[c][1][4*cc+1]);
          d0 = x2.x - y4.z; creg[c][0][4*cc+2] = fmaf(d0, d0, creg[c][0][4*cc+2]);
          d1 = x2.y - y4.z; creg[c][1][4*cc+2] = fmaf(d1, d1, creg[c][1][4*cc+2]);
          d0 = x2.x - y4.w; creg[c][0][4*cc+3] = fmaf(d0, d0, creg[c][0][4*cc+3]);
          d1 = x2.y - y4.w; creg[c][1][4*cc+3] = fmaf(d1, d1, creg[c][1][4*cc+3]);
        }
      }
    }
    // write C (raw), scale creg in place
    const size_t cb = (size_t)n * P * P;
#pragma unroll
    for (int r = 0; r < 2; ++r) {
      const size_t rowb = cb + (size_t)(TR * ti + r0 + r) * P + TC * tj;
#pragma unroll
      for (int cc = 0; cc < 8; ++cc) {
        vfloat4 c4 = {creg[c][r][4*cc+0], creg[c][r][4*cc+1],
                      creg[c][r][4*cc+2], creg[c][r][4*cc+3]};
        __builtin_nontemporal_store(c4, (vfloat4*)(Cout + rowb + 32*cc + 4*c8));
        creg[c][r][4*cc+0] *= SCALE;
        creg[c][r][4*cc+1] *= SCALE;
        creg[c][r][4*cc+2] *= SCALE;
        creg[c][r][4*cc+3] *= SCALE;
      }
    }
  }
  __syncthreads();  // build->iter LDS union hazard
  if (t < 256) { sm.vlds[0][t] = 0.f; sm.vlds[1][t] = 0.f; }  // V(0) = 0
  __syncthreads();

  // ---------------- pipelined dual-chain Sinkhorn iterations ----------------
  float* vlA = sm.vlds[0];
  float* vlB = sm.vlds[1];
  // prologue: u(0) for both chains (stamp 1, parity 1)
  u_stage(0, t, c8, r0, ti, tj, nA, creg[0], vlA, rp + RPF, rfA_mine);
  u_stage(0, t, c8, r0, ti, tj, nB, creg[1], vlB, rp + RPF, rfB_mine);
#pragma unroll 1
  for (int k = 0; k < MAX_ITER; ++k) {
    const int pw = (k + 1) & 1;   // parity of stamp k+1
    float* rpp = rp + pw * RPF;
    float* cpp = cp + pw * CPF;
    float* rpn = rp + (k & 1) * RPF;  // parity of stamp k+2
    row_merge(k, t, r0, ti, nA, U[0], rpp, rfA_band, sm, l2mu);
    v_stage(k, t, w, gg, c8, ti, tj, nA, creg[0], U[0], cpp, cfA_mine, sm);
    row_merge(k, t, r0, ti, nB, U[1], rpp, rfB_band, sm, l2mu);
    v_stage(k, t, w, gg, c8, ti, tj, nB, creg[1], U[1], cpp, cfB_mine, sm);
    col_merge(k, t, tj, nA, vlA, cpp, cfA_band, sm, l2mu);
    if (k + 1 < MAX_ITER)
      u_stage(k + 1, t, c8, r0, ti, tj, nA, creg[0], vlA, rpn, rfA_mine);
    col_merge(k, t, tj, nB, vlB, cpp, cfB_band, sm, l2mu);
    if (k + 1 < MAX_ITER)
      u_stage(k + 1, t, c8, r0, ti, tj, nB, creg[1], vlB, rpn, rfB_mine);
  }
  // here: U[c] = U(50) (from row_merge k=49), vlds[c] = V(50)

  // ---------------- epilogue: pi and cost ----------------
  // rp/cp live inside the pi region: GLOBAL rendezvous before overwrite
  if (t == 0) flag_store(&ef[b], 1u);
  if (t < 256) {
    while (flag_load(&ef[t]) < 1u) __builtin_amdgcn_s_sleep(1);
  }
  __syncthreads();
#pragma unroll
  for (int c = 0; c < 2; ++c) {
    const int n = 2 * g + c;
    float vv[32];
#pragma unroll
    for (int i = 0; i < 32; ++i)
      vv[i] = sm.vlds[c][32 * (i >> 2) + 4 * c8 + (i & 3)];
    float csum = 0.f;
#pragma unroll
    for (int r = 0; r < 2; ++r) {
      const size_t rowb = (size_t)n * P * P + (size_t)(TR*ti + r0 + r) * P + TC*tj;
#pragma unroll
      for (int cc = 0; cc < 8; ++cc) {
        vfloat4 p4;
        p4.x = EXP2(U[c][r] + vv[4*cc+0] - creg[c][r][4*cc+0]);
        p4.y = EXP2(U[c][r] + vv[4*cc+1] - creg[c][r][4*cc+1]);
        p4.z = EXP2(U[c][r] + vv[4*cc+2] - creg[c][r][4*cc+2]);
        p4.w = EXP2(U[c][r] + vv[4*cc+3] - creg[c][r][4*cc+3]);
        csum += p4.x * creg[c][r][4*cc+0] + p4.y * creg[c][r][4*cc+1]
              + p4.z * creg[c][r][4*cc+2] + p4.w * creg[c][r][4*cc+3];
        __builtin_nontemporal_store(p4, (vfloat4*)(pi + rowb + 32*cc + 4*c8));
      }
    }
    float cs = csum * C2N;  // creg = C*INV_EPS*log2e -> sum(pi*creg)*EPS*ln2
#pragma unroll
    for (int off = 32; off; off >>= 1) cs += __shfl_xor(cs, off);
    if (l == 0) atomicAdd(cost + n, cs);
  }
}

// ===========================================================================
// Fallback path (round-1 kernels, known-good) in case cooperative launch fails
// ===========================================================================
__global__ __launch_bounds__(256) void build_c(const float* __restrict__ x,
                                               const float* __restrict__ y,
                                               float* __restrict__ C,
                                               float* __restrict__ CT) {
  __shared__ float xs[DF][68];
  __shared__ float ys[DF][68];
  const int n = blockIdx.z;
  const int i0 = blockIdx.y * 64, j0 = blockIdx.x * 64;
  const int t = threadIdx.x;
  const int lr = t >> 4, c4 = (t & 15) * 4;
  const size_t xb = (size_t)n * P * DF;
  for (int rr = lr; rr < 64; rr += 16) {
    float4 xv = *(const float4*)(x + xb + (size_t)(i0 + rr) * DF + c4);
    float4 yv = *(const float4*)(y + xb + (size_t)(j0 + rr) * DF + c4);
    xs[c4 + 0][rr] = xv.x; xs[c4 + 1][rr] = xv.y;
    xs[c4 + 2][rr] = xv.z; xs[c4 + 3][rr] = xv.w;
    ys[c4 + 0][rr] = yv.x; ys[c4 + 1][rr] = yv.y;
    ys[c4 + 2][rr] = yv.z; ys[c4 + 3][rr] = yv.w;
  }
  __syncthreads();
  const int ty = t >> 4, tx = t & 15;
  float acc[4][4];
#pragma unroll
  for (int e = 0; e < 4; ++e)
#pragma unroll
    for (int f = 0; f < 4; ++f) acc[e][f] = 0.f;
#pragma unroll 4
  for (int d = 0; d < DF; ++d) {
    float4 a4 = *(const float4*)&xs[d][4 * ty];
    float4 b4 = *(const float4*)&ys[d][4 * tx];
    float av[4] = {a4.x, a4.y, a4.z, a4.w};
    float bv[4] = {b4.x, b4.y, b4.z, b4.w};
#pragma unroll
    for (int e = 0; e < 4; ++e)
#pragma unroll
      for (int f = 0; f < 4; ++f) {
        float df = av[e] - bv[f];
        acc[e][f] = fmaf(df, df, acc[e][f]);
      }
  }
  const size_t cbase = (size_t)n * P * P;
#pragma unroll
  for (int e = 0; e < 4; ++e) {
    float4 v4 = make_float4(acc[e][0], acc[e][1], acc[e][2], acc[e][3]);
    *(float4*)(C + cbase + (size_t)(i0 + 4 * ty + e) * P + (j0 + 4 * tx)) = v4;
  }
#pragma unroll
  for (int f = 0; f < 4; ++f) {
    float4 v4 = make_float4(acc[0][f], acc[1][f], acc[2][f], acc[3][f]);
    *(float4*)(CT + cbase + (size_t)(j0 + 4 * tx + f) * P + (i0 + 4 * ty)) = v4;
  }
}

__global__ __launch_bounds__(256) void lse_pass(const float* __restrict__ M,
                                                const float* __restrict__ wv_,
                                                float* __restrict__ out,
                                                float log_w) {
  __shared__ float red[8];
  const int b = blockIdx.x;
  const int n = b >> 11;
  const int t = threadIdx.x;
  const float4* row = (const float4*)(M + (size_t)b * P);
  const float4* wv = (const float4*)(wv_ + (size_t)n * P);
  float4 c0 = row[t], c1 = row[t + 256];
  float4 w0 = wv[t], w1 = wv[t + 256];
  float a[8];
  a[0] = (w0.x - c0.x) * INV_EPS; a[1] = (w0.y - c0.y) * INV_EPS;
  a[2] = (w0.z - c0.z) * INV_EPS; a[3] = (w0.w - c0.w) * INV_EPS;
  a[4] = (w1.x - c1.x) * INV_EPS; a[5] = (w1.y - c1.y) * INV_EPS;
  a[6] = (w1.z - c1.z) * INV_EPS; a[7] = (w1.w - c1.w) * INV_EPS;
  float mx = a[0];
#pragma unroll
  for (int k = 1; k < 8; ++k) mx = fmaxf(mx, a[k]);
#pragma unroll
  for (int o = 32; o > 0; o >>= 1) mx = fmaxf(mx, __shfl_xor(mx, o));
  if ((t & 63) == 0) red[t >> 6] = mx;
  __syncthreads();
  mx = fmaxf(fmaxf(red[0], red[1]), fmaxf(red[2], red[3]));
  float s = 0.f;
#pragma unroll
  for (int k = 0; k < 8; ++k) s += __expf(a[k] - mx);
#pragma unroll
  for (int o = 32; o > 0; o >>= 1) s += __shfl_xor(s, o);
  if ((t & 63) == 0) red[4 + (t >> 6)] = s;
  __syncthreads();
  if (t == 0) {
    float S = red[4] + red[5] + red[6] + red[7];
    out[b] = EPS * (log_w - (mx + __logf(S)));
  }
}

__global__ __launch_bounds__(256) void final_pass(const float* __restrict__ C,
                                                  const float* __restrict__ u,
                                                  const float* __restrict__ v,
                                                  float* __restrict__ pi,
                                                  float* __restrict__ cost) {
  __shared__ float red[4];
  const int b = blockIdx.x;
  const int n = b >> 11;
  const int t = threadIdx.x;
  const float ui = u[b];
  const float4* row = (const float4*)(C + (size_t)b * P);
  const float4* vv = (const float4*)(v + (size_t)n * P);
  float4* prow = (float4*)(pi + (size_t)b * P);
  float local = 0.f;
#pragma unroll
  for (int h = 0; h < 2; ++h) {
    float4 c = row[t + 256 * h];
    float4 vw = vv[t + 256 * h];
    float4 p;
    p.x = __expf((ui + vw.x - c.x) * INV_EPS);
    p.y = __expf((ui + vw.y - c.y) * INV_EPS);
    p.z = __expf((ui + vw.z - c.z) * INV_EPS);
    p.w = __expf((ui + vw.w - c.w) * INV_EPS);
    prow[t + 256 * h] = p;
    local += p.x * c.x + p.y * c.y + p.z * c.z + p.w * c.w;
  }
#pragma unroll
  for (int o = 32; o > 0; o >>= 1) local += __shfl_xor(local, o);
  if ((t & 63) == 0) red[t >> 6] = local;
  __syncthreads();
  if (t == 0) {
    float S = red[0] + red[1] + red[2] + red[3];
    atomicAdd(cost + n, S);
  }
}

extern "C" void kernel_launch(void* const* d_in, const int* in_sizes, int n_in,
                              void* d_out, int out_size, void* d_ws, size_t ws_size,
                              hipStream_t stream) {
  const float* x = (const float*)d_in[0];
  const float* y = (const float*)d_in[1];
  float* cost = (float*)d_out;                 // 4 floats
  float* pi = cost + 4;                        // 4*2048*2048
  float* C = pi + (size_t)NB * P * P;          // 4*2048*2048
  // scratch carved out of the pi output slot (fully overwritten by epilogue):
  float* rp = pi;                    // [2][RPF] row partials (512 KB)
  float* cp = pi + 2 * RPF;          // [2][CPF] col partials (1 MB)
  unsigned* flags = (unsigned*)d_ws; // rowflag[512] + colflag[512] + ef[256]

  (void)hipMemsetAsync(cost, 0, NB * sizeof(float), stream);
  (void)hipMemsetAsync(flags, 0, 5120, stream);

  float lmu = logf(1.0f / (float)P + 1e-8f);    // nat log (fallback)
  float l2mu = log2f(1.0f / (float)P + 1e-8f);  // base-2 log (main)

  void* args[] = {(void*)&x, (void*)&y, (void*)&C, (void*)&pi,
                  (void*)&cost, (void*)&rp, (void*)&cp, (void*)&flags,
                  (void*)&l2mu};
  hipError_t err = hipLaunchCooperativeKernel((void*)sinkhorn_all, dim3(NBLK),
                                              dim3(TPB), args, 0, stream);
  if (err != hipSuccess) {
    // fallback: round-1 multi-kernel path (deterministically taken if coop fails)
    float* u = (float*)d_ws;
    float* v = u + NB * P;
    (void)hipMemsetAsync(v, 0, NB * P * sizeof(float), stream);
    float* CT = pi;
    build_c<<<dim3(32, 32, 4), 256, 0, stream>>>(x, y, C, CT);
    for (int it = 0; it < MAX_ITER; ++it) {
      lse_pass<<<NB * P, 256, 0, stream>>>(C, v, u, lmu);
      lse_pass<<<NB * P, 256, 0, stream>>>(CT, u, v, lmu);
    }
    final_pass<<<NB * P, 256, 0, stream>>>(C, u, v, pi, cost);
  }
}